// Round 1
// baseline (146.732 us; speedup 1.0000x reference)
//
#include <hip/hip_runtime.h>
#include <hip/hip_bf16.h>

// Chamfer loss: pred [8,4096,3] f32, gt [8,4096,3] f32 -> scalar f32.
// loss = mean_b[ mean(d1)+mean(d2) + 3*(mean(top2048(d1)) + mean(top2048(d2))) ]
// d1[n] = sqrt(min_m ||p_n - g_m||^2), d2 symmetric.

#define BATCH 8
#define NPTS  4096
#define TOPK  2048
#define TQ    4      // queries per thread
#define BT    256    // threads per block
#define QCHUNK (BT * TQ)   // 1024 queries per block
#define DCHUNK 1024        // db points per block

// ---------------- Kernel A: min squared distance (one direction per z) -----
__global__ __launch_bounds__(BT) void nn_min_kernel(
    const float* __restrict__ pred, const float* __restrict__ gt,
    unsigned* __restrict__ minsq /* [2*BATCH][NPTS] as float bits */) {
  const int qc  = blockIdx.x;          // 0..3 query chunk
  const int dc  = blockIdx.y;          // 0..3 db chunk
  const int bz  = blockIdx.z;          // b*2 + dir
  const int b   = bz >> 1;
  const int dir = bz & 1;
  const float* q = (dir == 0 ? pred : gt) + (size_t)b * NPTS * 3;
  const float* g = (dir == 0 ? gt : pred) + (size_t)b * NPTS * 3;
  unsigned* outrow = minsq + (size_t)bz * NPTS;

  __shared__ float4 db[DCHUNK];
  const int tid = threadIdx.x;

  // stage db chunk into LDS as (x,y,z,|g|^2)
  for (int i = tid; i < DCHUNK; i += BT) {
    int gi = dc * DCHUNK + i;
    float x = g[3 * gi + 0];
    float y = g[3 * gi + 1];
    float z = g[3 * gi + 2];
    db[i] = make_float4(x, y, z, x * x + y * y + z * z);
  }

  // load this thread's queries
  float qx[TQ], qy[TQ], qz[TQ], qn[TQ], m[TQ];
#pragma unroll
  for (int j = 0; j < TQ; j++) {
    int qi = qc * QCHUNK + tid + BT * j;
    qx[j] = q[3 * qi + 0];
    qy[j] = q[3 * qi + 1];
    qz[j] = q[3 * qi + 2];
    qn[j] = qx[j] * qx[j] + qy[j] * qy[j] + qz[j] * qz[j];
    m[j]  = 3.0e38f;
  }
  __syncthreads();

  for (int i = 0; i < DCHUNK; i++) {
    float4 gp = db[i];   // uniform address -> broadcast, no bank conflicts
#pragma unroll
    for (int j = 0; j < TQ; j++) {
      float dot = qx[j] * gp.x + qy[j] * gp.y + qz[j] * gp.z;
      float sq  = (qn[j] + gp.w) - 2.0f * dot;
      m[j] = fminf(m[j], sq);
    }
  }

#pragma unroll
  for (int j = 0; j < TQ; j++) {
    int qi = qc * QCHUNK + tid + BT * j;
    unsigned bits = __float_as_uint(fmaxf(m[j], 0.0f));  // nonneg: uint order == float order
    atomicMin(&outrow[qi], bits);
  }
}

// ---------------- Kernel B: sqrt + mean + exact top-k mean per row ---------
__global__ __launch_bounds__(BT) void select_kernel(
    const float* __restrict__ minsq, float* __restrict__ partials) {
  const int row = blockIdx.x;                // 0..15 = b*2+dir
  const float* src = minsq + (size_t)row * NPTS;
  const int tid = threadIdx.x;

  __shared__ float sf[4];
  __shared__ int   si[4];

  const int PER = NPTS / BT;  // 16 values per thread
  float d[PER];
  float sum_all = 0.0f;
#pragma unroll
  for (int j = 0; j < PER; j++) {
    float v = sqrtf(src[tid + BT * j]);
    d[j] = v;
    sum_all += v;
  }

  // block float sum of sum_all
  {
    float v = sum_all;
    for (int off = 32; off > 0; off >>= 1) v += __shfl_down(v, off);
    if ((tid & 63) == 0) sf[tid >> 6] = v;
    __syncthreads();
    sum_all = sf[0] + sf[1] + sf[2] + sf[3];
    __syncthreads();
  }

  // radix-select the TOPK-th largest value (exact, over float bit patterns)
  unsigned sel = 0u;
  for (int bit = 30; bit >= 0; --bit) {   // sign bit is 0 (nonneg)
    unsigned cand = sel | (1u << bit);
    int c = 0;
#pragma unroll
    for (int j = 0; j < PER; j++) c += (__float_as_uint(d[j]) >= cand) ? 1 : 0;
    for (int off = 32; off > 0; off >>= 1) c += __shfl_down(c, off);
    if ((tid & 63) == 0) si[tid >> 6] = c;
    __syncthreads();
    int total = si[0] + si[1] + si[2] + si[3];
    __syncthreads();
    if (total >= TOPK) sel = cand;
  }

  // sum of strictly-greater values + count
  int cgt = 0;
  float sgt = 0.0f;
#pragma unroll
  for (int j = 0; j < PER; j++) {
    if (__float_as_uint(d[j]) > sel) { cgt++; sgt += d[j]; }
  }
  {
    float v = sgt;
    for (int off = 32; off > 0; off >>= 1) v += __shfl_down(v, off);
    if ((tid & 63) == 0) sf[tid >> 6] = v;
    int c = cgt;
    for (int off = 32; off > 0; off >>= 1) c += __shfl_down(c, off);
    if ((tid & 63) == 0) si[tid >> 6] = c;
    __syncthreads();
    sgt = sf[0] + sf[1] + sf[2] + sf[3];
    cgt = si[0] + si[1] + si[2] + si[3];
  }

  if (tid == 0) {
    float kth = __uint_as_float(sel);
    float topk_sum = sgt + (float)(TOPK - cgt) * kth;  // tie-exact vs lax.top_k
    partials[row] = sum_all / (float)NPTS + 3.0f * (topk_sum / (float)TOPK);
  }
}

// ---------------- Kernel C: final combine ----------------------------------
__global__ void final_kernel(const float* __restrict__ partials,
                             float* __restrict__ out) {
  float v = (threadIdx.x < 2 * BATCH) ? partials[threadIdx.x] : 0.0f;
  for (int off = 32; off > 0; off >>= 1) v += __shfl_down(v, off);
  if (threadIdx.x == 0) out[0] = v / (float)BATCH;
}

extern "C" void kernel_launch(void* const* d_in, const int* in_sizes, int n_in,
                              void* d_out, int out_size, void* d_ws, size_t ws_size,
                              hipStream_t stream) {
  const float* pred = (const float*)d_in[0];
  const float* gt   = (const float*)d_in[1];
  float* out = (float*)d_out;

  unsigned* minsq   = (unsigned*)d_ws;                       // [16][4096] float bits
  float*    partials = (float*)d_ws + 2 * BATCH * NPTS;      // [16]

  // sentinel: 0x7F7F7F7F ~= 3.39e38 as float, larger than any real sq-dist
  hipMemsetAsync(d_ws, 0x7F, (size_t)2 * BATCH * NPTS * sizeof(float), stream);

  dim3 gridA(NPTS / QCHUNK, NPTS / DCHUNK, 2 * BATCH);  // (4,4,16)
  nn_min_kernel<<<gridA, BT, 0, stream>>>(pred, gt, minsq);
  select_kernel<<<2 * BATCH, BT, 0, stream>>>((const float*)minsq, partials);
  final_kernel<<<1, 64, 0, stream>>>(partials, out);
}

// Round 2
// 97.869 us; speedup vs baseline: 1.4993x; 1.4993x over previous
//
#include <hip/hip_runtime.h>
#include <hip/hip_bf16.h>

// Chamfer loss: pred [8,4096,3] f32, gt [8,4096,3] f32 -> scalar f32.
// loss = mean_b[ mean(d1)+mean(d2) + 3*(mean(top2048(d1)) + mean(top2048(d2))) ]
// d1[n] = sqrt(min_m ||p_n - g_m||^2), d2 symmetric.

#define BATCH 8
#define NPTS  4096
#define TOPK  2048
#define TQ    4      // queries per thread
#define BT    256    // threads per block
#define QCHUNK (BT * TQ)   // 1024 queries per block
#define DCHUNK 256         // db points per block (16 dc chunks -> 4 blocks/CU)

// ---------------- Kernel A: min squared distance (one direction per z) -----
// grid (4,16,16) = 1024 blocks -> ~4 blocks/CU, 16 waves/CU, 4 waves/SIMD:
// enough TLP to hide LDS latency (round-1 run at 1 wave/SIMD was latency-bound,
// OccupancyPercent 9.5, 85us).
__global__ __launch_bounds__(BT) void nn_min_kernel(
    const float* __restrict__ pred, const float* __restrict__ gt,
    unsigned* __restrict__ minsq /* [2*BATCH][NPTS] as float bits */) {
  const int qc  = blockIdx.x;          // 0..3 query chunk
  const int dc  = blockIdx.y;          // 0..15 db chunk
  const int bz  = blockIdx.z;          // b*2 + dir
  const int b   = bz >> 1;
  const int dir = bz & 1;
  const float* q = (dir == 0 ? pred : gt) + (size_t)b * NPTS * 3;
  const float* g = (dir == 0 ? gt : pred) + (size_t)b * NPTS * 3;
  unsigned* outrow = minsq + (size_t)bz * NPTS;

  // db chunk staged as (-2x, -2y, -2z, |g|^2): inner loop is then
  // t = qn + gn; 3x fma; fmin  -> 5 VALU per pair.
  __shared__ float4 db[DCHUNK];
  const int tid = threadIdx.x;

  {
    int gi = dc * DCHUNK + tid;        // one point per thread
    float x = g[3 * gi + 0];
    float y = g[3 * gi + 1];
    float z = g[3 * gi + 2];
    db[tid] = make_float4(-2.0f * x, -2.0f * y, -2.0f * z,
                          x * x + y * y + z * z);
  }

  // load this thread's queries
  float qx[TQ], qy[TQ], qz[TQ], qn[TQ], m[TQ];
#pragma unroll
  for (int j = 0; j < TQ; j++) {
    int qi = qc * QCHUNK + tid + BT * j;
    qx[j] = q[3 * qi + 0];
    qy[j] = q[3 * qi + 1];
    qz[j] = q[3 * qi + 2];
    qn[j] = qx[j] * qx[j] + qy[j] * qy[j] + qz[j] * qz[j];
    m[j]  = 3.0e38f;
  }
  __syncthreads();

#pragma unroll 4
  for (int i = 0; i < DCHUNK; i++) {
    float4 gp = db[i];   // uniform address -> broadcast, no bank conflicts
#pragma unroll
    for (int j = 0; j < TQ; j++) {
      float t = qn[j] + gp.w;
      t = fmaf(gp.x, qx[j], t);
      t = fmaf(gp.y, qy[j], t);
      t = fmaf(gp.z, qz[j], t);
      m[j] = fminf(m[j], t);
    }
  }

#pragma unroll
  for (int j = 0; j < TQ; j++) {
    int qi = qc * QCHUNK + tid + BT * j;
    unsigned bits = __float_as_uint(fmaxf(m[j], 0.0f));  // nonneg: uint order == float order
    atomicMin(&outrow[qi], bits);
  }
}

// ---------------- Kernel B: sqrt + mean + exact top-k mean per row ---------
__global__ __launch_bounds__(BT) void select_kernel(
    const float* __restrict__ minsq, float* __restrict__ partials) {
  const int row = blockIdx.x;                // 0..15 = b*2+dir
  const float* src = minsq + (size_t)row * NPTS;
  const int tid = threadIdx.x;

  __shared__ float sf[4];
  __shared__ int   si[4];

  const int PER = NPTS / BT;  // 16 values per thread
  float d[PER];
  float sum_all = 0.0f;
#pragma unroll
  for (int j = 0; j < PER; j++) {
    float v = sqrtf(src[tid + BT * j]);
    d[j] = v;
    sum_all += v;
  }

  // block float sum of sum_all
  {
    float v = sum_all;
    for (int off = 32; off > 0; off >>= 1) v += __shfl_down(v, off);
    if ((tid & 63) == 0) sf[tid >> 6] = v;
    __syncthreads();
    sum_all = sf[0] + sf[1] + sf[2] + sf[3];
    __syncthreads();
  }

  // radix-select the TOPK-th largest value (exact, over float bit patterns)
  unsigned sel = 0u;
  for (int bit = 30; bit >= 0; --bit) {   // sign bit is 0 (nonneg)
    unsigned cand = sel | (1u << bit);
    int c = 0;
#pragma unroll
    for (int j = 0; j < PER; j++) c += (__float_as_uint(d[j]) >= cand) ? 1 : 0;
    for (int off = 32; off > 0; off >>= 1) c += __shfl_down(c, off);
    if ((tid & 63) == 0) si[tid >> 6] = c;
    __syncthreads();
    int total = si[0] + si[1] + si[2] + si[3];
    __syncthreads();
    if (total >= TOPK) sel = cand;
  }

  // sum of strictly-greater values + count
  int cgt = 0;
  float sgt = 0.0f;
#pragma unroll
  for (int j = 0; j < PER; j++) {
    if (__float_as_uint(d[j]) > sel) { cgt++; sgt += d[j]; }
  }
  {
    float v = sgt;
    for (int off = 32; off > 0; off >>= 1) v += __shfl_down(v, off);
    if ((tid & 63) == 0) sf[tid >> 6] = v;
    int c = cgt;
    for (int off = 32; off > 0; off >>= 1) c += __shfl_down(c, off);
    if ((tid & 63) == 0) si[tid >> 6] = c;
    __syncthreads();
    sgt = sf[0] + sf[1] + sf[2] + sf[3];
    cgt = si[0] + si[1] + si[2] + si[3];
  }

  if (tid == 0) {
    float kth = __uint_as_float(sel);
    float topk_sum = sgt + (float)(TOPK - cgt) * kth;  // tie-exact vs lax.top_k
    partials[row] = sum_all / (float)NPTS + 3.0f * (topk_sum / (float)TOPK);
  }
}

// ---------------- Kernel C: final combine ----------------------------------
__global__ void final_kernel(const float* __restrict__ partials,
                             float* __restrict__ out) {
  float v = (threadIdx.x < 2 * BATCH) ? partials[threadIdx.x] : 0.0f;
  for (int off = 32; off > 0; off >>= 1) v += __shfl_down(v, off);
  if (threadIdx.x == 0) out[0] = v / (float)BATCH;
}

extern "C" void kernel_launch(void* const* d_in, const int* in_sizes, int n_in,
                              void* d_out, int out_size, void* d_ws, size_t ws_size,
                              hipStream_t stream) {
  const float* pred = (const float*)d_in[0];
  const float* gt   = (const float*)d_in[1];
  float* out = (float*)d_out;

  unsigned* minsq    = (unsigned*)d_ws;                      // [16][4096] float bits
  float*    partials = (float*)d_ws + 2 * BATCH * NPTS;      // [16]

  // sentinel: 0x7F7F7F7F ~= 3.39e38 as float, larger than any real sq-dist
  hipMemsetAsync(d_ws, 0x7F, (size_t)2 * BATCH * NPTS * sizeof(float), stream);

  dim3 gridA(NPTS / QCHUNK, NPTS / DCHUNK, 2 * BATCH);  // (4,16,16) = 1024 blocks
  nn_min_kernel<<<gridA, BT, 0, stream>>>(pred, gt, minsq);
  select_kernel<<<2 * BATCH, BT, 0, stream>>>((const float*)minsq, partials);
  final_kernel<<<1, 64, 0, stream>>>(partials, out);
}